// Round 16
// baseline (168.307 us; speedup 1.0000x reference)
//
#include <hip/hip_runtime.h>
#include <hip/hip_bf16.h>

#define NFEAT 9
#define VOCAB 119
#define HIDDEN 128
#define NHEAD 8
#define HDIM 16
#define KNBR 16

typedef __attribute__((ext_vector_type(8))) short short8;   // 8 bf16 = 4 VGPRs
typedef __attribute__((ext_vector_type(4))) float f32x4;    // MFMA C/D

// ---------- async global->LDS, 16B per lane (dest = wave-uniform base + lane*16) ----------
__device__ __forceinline__ void load_lds16(const void* g, void* l) {
    __builtin_amdgcn_global_load_lds((const __attribute__((address_space(1))) void*)g,
                                     (__attribute__((address_space(3))) void*)l, 16, 0, 0);
}

// butterfly helper over 16-lane groups; offset must be an IMMEDIATE ->
// template parameter (r15 failed compiling it as a runtime arg).
template <int OFFS>
__device__ __forceinline__ float swz_xor(float v) {
    int r = __builtin_amdgcn_ds_swizzle(__float_as_int(v), OFFS);
    return __int_as_float(r);
}

// ---------- sentinel fill (distinguishable failure signatures) ----------
__global__ void fill_kernel(float* out, int n, float val) {
    int i = blockIdx.x * blockDim.x + threadIdx.x;
    if (i < n) out[i] = val;
}

// ---------- Kernel 0: W -> W^T bf16 (one-time per launch, 12 blocks) ----------
__global__ __launch_bounds__(256) void wt_kernel(
    const float* __restrict__ Wq, const float* __restrict__ Wk,
    const float* __restrict__ Wv, short* __restrict__ Wt)
{
    int mat = blockIdx.x >> 2, tile = blockIdx.x & 3;  // 3 mats x 4 row-tiles
    const float* W = (mat == 0) ? Wq : (mat == 1) ? Wk : Wv;
    __shared__ float ls[32 * HIDDEN];
    int tid = threadIdx.x;
    int cc0 = tile * 32;
    #pragma unroll
    for (int j = 0; j < 16; ++j) {
        int idx = j * 256 + tid;
        ls[idx] = W[(size_t)cc0 * HIDDEN + idx];   // coalesced
    }
    __syncthreads();
    int c = tid & 127, hf = tid >> 7;  // thread: output row c, 16 cc's
    unsigned int ob[8];
    #pragma unroll
    for (int j = 0; j < 8; ++j) {
        int ccl = hf * 16 + 2 * j;
        __hip_bfloat16 b0 = __float2bfloat16(ls[ccl * HIDDEN + c]);
        __hip_bfloat16 b1 = __float2bfloat16(ls[(ccl + 1) * HIDDEN + c]);
        ob[j] = (unsigned int)*reinterpret_cast<unsigned short*>(&b0)
              | ((unsigned int)*reinterpret_cast<unsigned short*>(&b1) << 16);
    }
    unsigned int* dst = reinterpret_cast<unsigned int*>(
        Wt + (size_t)mat * HIDDEN * HIDDEN + (size_t)c * HIDDEN + cc0 + hf * 16);
    #pragma unroll
    for (int j = 0; j < 8; ++j) dst[j] = ob[j];
}

// ---------- Kernel 1: fused encoder + MFMA QKV (FROZEN from r14) ----------
#define MT 32
#define HBS 136  // padded bf16 row stride; 2-way LDS aliasing = free (m136)

__global__ __launch_bounds__(256, 3) void qkv_kernel(
    const int* __restrict__ X, const float* __restrict__ emb,
    const short* __restrict__ Wt,
    const float* __restrict__ bq, const float* __restrict__ bk,
    const float* __restrict__ bv,
    float* __restrict__ qf, __hip_bfloat16* __restrict__ kv, int N)
{
    __shared__ __align__(16) short hb[MT * HBS];
    __shared__ int xs[MT * NFEAT];

    const int tid = threadIdx.x;
    const int n0 = blockIdx.x * MT;

    for (int i = tid; i < MT * NFEAT; i += 256) {
        int n = n0 + i / NFEAT;
        int v = (n < N) ? X[(size_t)n * NFEAT + (i % NFEAT)] : 0;
        xs[i] = min(max(v, 0), VOCAB - 1);  // clamp: never fault
    }
    __syncthreads();

    {
        const int cg = tid & 31;        // 32 groups x 4 channels
        const int slot = tid >> 5;      // 8 slots x 4 nodes
        #pragma unroll
        for (int i = 0; i < 4; ++i) {
            int nl = slot * 4 + i;
            float4 acc = {0.f, 0.f, 0.f, 0.f};
            #pragma unroll
            for (int f = 0; f < NFEAT; ++f) {
                const float4 e = *reinterpret_cast<const float4*>(
                    &emb[((size_t)f * VOCAB + xs[nl * NFEAT + f]) * HIDDEN + cg * 4]);
                acc.x += e.x; acc.y += e.y; acc.z += e.z; acc.w += e.w;
            }
            __hip_bfloat162 p0 = __float22bfloat162_rn(make_float2(acc.x, acc.y));
            __hip_bfloat162 p1 = __float22bfloat162_rn(make_float2(acc.z, acc.w));
            uint2 u;
            u.x = *reinterpret_cast<unsigned int*>(&p0);
            u.y = *reinterpret_cast<unsigned int*>(&p1);
            *reinterpret_cast<uint2*>(&hb[nl * HBS + cg * 4]) = u;  // 8B aligned
        }
    }
    __syncthreads();  // hb ready

    const int wave = tid >> 6, lane = tid & 63;
    const int l15 = lane & 15, quad = lane >> 4;

    // B stationary: wave owns channel groups wave*2, wave*2+1 (once per block)
    short8 b[2][3][4];
    float bias[2][3];
    #pragma unroll
    for (int g = 0; g < 2; ++g) {
        const int n = (wave * 2 + g) * 16 + l15;   // output channel
        #pragma unroll
        for (int mat = 0; mat < 3; ++mat) {
            #pragma unroll
            for (int k0 = 0; k0 < 4; ++k0)
                b[g][mat][k0] = *reinterpret_cast<const short8*>(
                    &Wt[(size_t)mat * HIDDEN * HIDDEN + n * HIDDEN + k0 * 32 + quad * 8]);
            bias[g][mat] = (mat == 0) ? bq[n] : (mat == 1) ? bk[n] : bv[n];
        }
    }

    #pragma unroll
    for (int mt = 0; mt < 2; ++mt) {
        const int mloc = mt * 16 + l15;          // A row (node within block)
        short8 a[4];
        #pragma unroll
        for (int k0 = 0; k0 < 4; ++k0)           // A[m][k=k0*32+quad*8..+7]
            a[k0] = *reinterpret_cast<const short8*>(
                &hb[mloc * HBS + k0 * 32 + quad * 8]);
        #pragma unroll
        for (int g = 0; g < 2; ++g) {
            const int n = (wave * 2 + g) * 16 + l15;
            f32x4 acc[3] = {{0.f,0.f,0.f,0.f},{0.f,0.f,0.f,0.f},{0.f,0.f,0.f,0.f}};
            #pragma unroll
            for (int mat = 0; mat < 3; ++mat)
                #pragma unroll
                for (int k0 = 0; k0 < 4; ++k0)
                    acc[mat] = __builtin_amdgcn_mfma_f32_16x16x32_bf16(
                        a[k0], b[g][mat][k0], acc[mat], 0, 0, 0);
            #pragma unroll
            for (int mat = 0; mat < 3; ++mat) {
                #pragma unroll
                for (int r = 0; r < 4; ++r) {    // C row = quad*4+r (node in m-tile)
                    int node = n0 + mt * 16 + quad * 4 + r;
                    if (node < N) {
                        float val = acc[mat][r] + bias[g][mat];
                        if (mat == 0)      qf[(size_t)node * HIDDEN + n] = val * 0.25f;
                        else if (mat == 1) kv[(size_t)node * 256 + n] = __float2bfloat16(val);
                        else               kv[(size_t)node * 256 + 128 + n] = __float2bfloat16(val);
                    }
                }
            }
        }
    }
}

// ---------------- Kernel 2: ELL sparse attention (r16: swizzle softmax) ----------------
// r14 counters: VALUBusy 80% — the inline-PV softmax recomputed max/exp/denom
// 16x per (node,head) (2048 v_exp/node for 128 needed). Now: softmax computed
// ONCE in the score phase via ds_swizzle butterfly over the 16 contiguous
// kk-lanes per head (xor 1,2,4,8 within 16-lane groups — LDS pipe, not VALU);
// sl holds final weights; PV = 16 broadcast reads + cvt + FMA.
#define NPB2 2
#define PAIRW 520  // bf16 elems per row-pair slot: 2*256 + 8 pad (1040B, 260 words)

__global__ __launch_bounds__(256) void attn_kernel(
    const int* __restrict__ nbr_idx, const int* __restrict__ nbr_mask,
    const float* __restrict__ qf, const __hip_bfloat16* __restrict__ kv,
    float* __restrict__ out, int N)
{
    __shared__ __align__(16) __hip_bfloat16 kvp[NPB2][8][PAIRW];
    __shared__ float sl[NPB2][KNBR][NHEAD + 1];
    __shared__ int idxl[NPB2][KNBR];
    __shared__ int mskl[NPB2][KNBR];

    const int tid = threadIdx.x;
    const int local = tid >> 7; // node within block
    const int t = tid & 127;    // thread within node
    int n = blockIdx.x * NPB2 + local;
    if (n >= N) n = N - 1;  // duplicate work, barrier-safe

    if (t < KNBR) {
        int iv = nbr_idx[(size_t)n * KNBR + t];
        idxl[local][t] = min(max(iv, 0), N - 1);
        mskl[local][t] = nbr_mask[(size_t)n * KNBR + t];
    }
    __syncthreads();

    const int hh = t >> 4;   // head (0..7)
    const int kk = t & 15;   // neighbor (scores) / dd (PV)

    float qr[HDIM];
    {
        const float4* qp = reinterpret_cast<const float4*>(
            qf + (size_t)n * HIDDEN + hh * HDIM);
        #pragma unroll
        for (int c4 = 0; c4 < 4; ++c4) {
            float4 qv = qp[c4];
            qr[4 * c4 + 0] = qv.x; qr[4 * c4 + 1] = qv.y;
            qr[4 * c4 + 2] = qv.z; qr[4 * c4 + 3] = qv.w;
        }
    }

    // gather: 4 pair-loads per wave; k-half lanes predicated on mask
    {
        const int w2 = t >> 6;       // uniform per wave
        const int l = t & 63;
        #pragma unroll
        for (int j = 0; j < 4; ++j) {
            int pair = 2 * j + w2;
            int r = pair * 2 + (l >> 5);          // neighbor row this lane feeds
            bool khalf = (l & 31) < 16;           // first 256B = k
            if (!khalf || mskl[local][r]) {
                const short* src = (const short*)kv
                    + (size_t)idxl[local][r] * 256 + (size_t)(l & 31) * 8;
                load_lds16(src, &kvp[local][pair][0]);  // + lane*16 implicit
            }
        }
    }
    __syncthreads();

    // scores + butterfly softmax: thread (hh, kk); kk = low 4 lane bits ->
    // the 16 kk-lanes per head are contiguous; xor-swizzles stay in-group.
    {
        const short8* kb = reinterpret_cast<const short8*>(
            &kvp[local][kk >> 1][(kk & 1) * 256 + hh * HDIM]);
        short8 k0 = kb[0], k1 = kb[1];
        const __hip_bfloat162* kp0 = reinterpret_cast<const __hip_bfloat162*>(&k0);
        const __hip_bfloat162* kp1 = reinterpret_cast<const __hip_bfloat162*>(&k1);
        float s = 0.f;
        #pragma unroll
        for (int d2 = 0; d2 < 4; ++d2) {
            float2 f0 = __bfloat1622float2(kp0[d2]);
            float2 f1 = __bfloat1622float2(kp1[d2]);
            s += qr[2 * d2] * f0.x + qr[2 * d2 + 1] * f0.y;
            s += qr[8 + 2 * d2] * f1.x + qr[8 + 2 * d2 + 1] * f1.y;
        }
        if (!mskl[local][kk]) s = -1e9f;
        // max over the 16 kk-lanes (BitMode offsets: xor<<10 | and 0x1F)
        float m = s;
        m = fmaxf(m, swz_xor<0x041F>(m));
        m = fmaxf(m, swz_xor<0x081F>(m));
        m = fmaxf(m, swz_xor<0x101F>(m));
        m = fmaxf(m, swz_xor<0x201F>(m));
        float e = __expf(s - m);
        float d = e;
        d += swz_xor<0x041F>(d);
        d += swz_xor<0x081F>(d);
        d += swz_xor<0x101F>(d);
        d += swz_xor<0x201F>(d);
        sl[local][kk][hh] = e / d;   // final weight; all-masked -> 1/16 exact
    }
    __syncthreads();

    // PV: thread (hh, dd=kk); weights precomputed -> reads + cvt + FMA only
    {
        const int dd = kk;
        float o = 0.f;
        #pragma unroll
        for (int j = 0; j < KNBR; ++j) {
            float w = sl[local][j][hh];   // broadcast within dd-group (free)
            float vv = __bfloat162float(
                kvp[local][j >> 1][(j & 1) * 256 + HIDDEN + hh * HDIM + dd]);
            o += w * vv;
        }
        out[(size_t)n * HIDDEN + t] = o;  // OUTPUT IS FLOAT32 (verified r6)
    }
}

extern "C" void kernel_launch(void* const* d_in, const int* in_sizes, int n_in,
                              void* d_out, int out_size, void* d_ws, size_t ws_size,
                              hipStream_t stream)
{
    float* out = (float*)d_out;

    bool ok = (n_in == 10);
    int N = ok ? in_sizes[0] / NFEAT : 0;
    ok = ok && N > 0 && in_sizes[0] == N * NFEAT
            && in_sizes[1] == N * KNBR
            && in_sizes[2] == N * KNBR
            && in_sizes[3] == NFEAT * VOCAB * HIDDEN
            && in_sizes[4] == HIDDEN * HIDDEN && in_sizes[5] == HIDDEN
            && in_sizes[6] == HIDDEN * HIDDEN && in_sizes[7] == HIDDEN
            && in_sizes[8] == HIDDEN * HIDDEN && in_sizes[9] == HIDDEN
            && out_size == N * HIDDEN;
    if (!ok) {
        fill_kernel<<<(out_size + 255) / 256, 256, 0, stream>>>(out, out_size, 0.0f);
        return;
    }
    size_t need = (size_t)N * 1024 + 3 * HIDDEN * HIDDEN * sizeof(short);
    if (ws_size < need) {
        fill_kernel<<<(out_size + 255) / 256, 256, 0, stream>>>(out, out_size, 1.0f);
        return;
    }

    const int* X        = (const int*)d_in[0];
    const int* nbr_idx  = (const int*)d_in[1];
    const int* nbr_mask = (const int*)d_in[2];
    const float* emb = (const float*)d_in[3];
    const float* Wq  = (const float*)d_in[4];
    const float* bq  = (const float*)d_in[5];
    const float* Wk  = (const float*)d_in[6];
    const float* bk  = (const float*)d_in[7];
    const float* Wv  = (const float*)d_in[8];
    const float* bv  = (const float*)d_in[9];

    // workspace: qf fp32 [N][128] | kv bf16 [N][256] | Wt bf16 [3][128][128]
    float* qf = (float*)d_ws;
    __hip_bfloat16* kv =
        (__hip_bfloat16*)((char*)d_ws + (size_t)N * HIDDEN * sizeof(float));
    short* Wt = (short*)((char*)d_ws + (size_t)N * 1024);

    wt_kernel<<<12, 256, 0, stream>>>(Wq, Wk, Wv, Wt);
    qkv_kernel<<<(N + MT - 1) / MT, 256, 0, stream>>>(
        X, emb, Wt, bq, bk, bv, qf, kv, N);
    attn_kernel<<<(N + NPB2 - 1) / NPB2, 256, 0, stream>>>(
        nbr_idx, nbr_mask, qf, kv, out, N);
}

// Round 17
// 166.109 us; speedup vs baseline: 1.0132x; 1.0132x over previous
//
#include <hip/hip_runtime.h>
#include <hip/hip_bf16.h>

#define NFEAT 9
#define VOCAB 119
#define HIDDEN 128
#define NHEAD 8
#define HDIM 16
#define KNBR 16

typedef __attribute__((ext_vector_type(8))) short short8;   // 8 bf16 = 4 VGPRs
typedef __attribute__((ext_vector_type(4))) float f32x4;    // MFMA C/D

// ---------- async global->LDS, 16B per lane (dest = wave-uniform base + lane*16) ----------
__device__ __forceinline__ void load_lds16(const void* g, void* l) {
    __builtin_amdgcn_global_load_lds((const __attribute__((address_space(1))) void*)g,
                                     (__attribute__((address_space(3))) void*)l, 16, 0, 0);
}

// butterfly helper over 16-lane groups; offset must be an IMMEDIATE (template)
template <int OFFS>
__device__ __forceinline__ float swz_xor(float v) {
    int r = __builtin_amdgcn_ds_swizzle(__float_as_int(v), OFFS);
    return __int_as_float(r);
}

// ---------- sentinel fill (distinguishable failure signatures) ----------
__global__ void fill_kernel(float* out, int n, float val) {
    int i = blockIdx.x * blockDim.x + threadIdx.x;
    if (i < n) out[i] = val;
}

// ---------- Kernel 0: W -> W^T bf16 (one-time per launch, 12 blocks) ----------
__global__ __launch_bounds__(256) void wt_kernel(
    const float* __restrict__ Wq, const float* __restrict__ Wk,
    const float* __restrict__ Wv, short* __restrict__ Wt)
{
    int mat = blockIdx.x >> 2, tile = blockIdx.x & 3;  // 3 mats x 4 row-tiles
    const float* W = (mat == 0) ? Wq : (mat == 1) ? Wk : Wv;
    __shared__ float ls[32 * HIDDEN];
    int tid = threadIdx.x;
    int cc0 = tile * 32;
    #pragma unroll
    for (int j = 0; j < 16; ++j) {
        int idx = j * 256 + tid;
        ls[idx] = W[(size_t)cc0 * HIDDEN + idx];   // coalesced
    }
    __syncthreads();
    int c = tid & 127, hf = tid >> 7;  // thread: output row c, 16 cc's
    unsigned int ob[8];
    #pragma unroll
    for (int j = 0; j < 8; ++j) {
        int ccl = hf * 16 + 2 * j;
        __hip_bfloat16 b0 = __float2bfloat16(ls[ccl * HIDDEN + c]);
        __hip_bfloat16 b1 = __float2bfloat16(ls[(ccl + 1) * HIDDEN + c]);
        ob[j] = (unsigned int)*reinterpret_cast<unsigned short*>(&b0)
              | ((unsigned int)*reinterpret_cast<unsigned short*>(&b1) << 16);
    }
    unsigned int* dst = reinterpret_cast<unsigned int*>(
        Wt + (size_t)mat * HIDDEN * HIDDEN + (size_t)c * HIDDEN + cc0 + hf * 16);
    #pragma unroll
    for (int j = 0; j < 8; ++j) dst[j] = ob[j];
}

// ---------- Kernel 1: fused encoder + MFMA QKV (FROZEN from r14) ----------
#define MT 32
#define HBS 136  // padded bf16 row stride; 2-way LDS aliasing = free (m136)

__global__ __launch_bounds__(256, 3) void qkv_kernel(
    const int* __restrict__ X, const float* __restrict__ emb,
    const short* __restrict__ Wt,
    const float* __restrict__ bq, const float* __restrict__ bk,
    const float* __restrict__ bv,
    float* __restrict__ qf, __hip_bfloat16* __restrict__ kv, int N)
{
    __shared__ __align__(16) short hb[MT * HBS];
    __shared__ int xs[MT * NFEAT];

    const int tid = threadIdx.x;
    const int n0 = blockIdx.x * MT;

    for (int i = tid; i < MT * NFEAT; i += 256) {
        int n = n0 + i / NFEAT;
        int v = (n < N) ? X[(size_t)n * NFEAT + (i % NFEAT)] : 0;
        xs[i] = min(max(v, 0), VOCAB - 1);  // clamp: never fault
    }
    __syncthreads();

    {
        const int cg = tid & 31;        // 32 groups x 4 channels
        const int slot = tid >> 5;      // 8 slots x 4 nodes
        #pragma unroll
        for (int i = 0; i < 4; ++i) {
            int nl = slot * 4 + i;
            float4 acc = {0.f, 0.f, 0.f, 0.f};
            #pragma unroll
            for (int f = 0; f < NFEAT; ++f) {
                const float4 e = *reinterpret_cast<const float4*>(
                    &emb[((size_t)f * VOCAB + xs[nl * NFEAT + f]) * HIDDEN + cg * 4]);
                acc.x += e.x; acc.y += e.y; acc.z += e.z; acc.w += e.w;
            }
            __hip_bfloat162 p0 = __float22bfloat162_rn(make_float2(acc.x, acc.y));
            __hip_bfloat162 p1 = __float22bfloat162_rn(make_float2(acc.z, acc.w));
            uint2 u;
            u.x = *reinterpret_cast<unsigned int*>(&p0);
            u.y = *reinterpret_cast<unsigned int*>(&p1);
            *reinterpret_cast<uint2*>(&hb[nl * HBS + cg * 4]) = u;  // 8B aligned
        }
    }
    __syncthreads();  // hb ready

    const int wave = tid >> 6, lane = tid & 63;
    const int l15 = lane & 15, quad = lane >> 4;

    // B stationary: wave owns channel groups wave*2, wave*2+1 (once per block)
    short8 b[2][3][4];
    float bias[2][3];
    #pragma unroll
    for (int g = 0; g < 2; ++g) {
        const int n = (wave * 2 + g) * 16 + l15;   // output channel
        #pragma unroll
        for (int mat = 0; mat < 3; ++mat) {
            #pragma unroll
            for (int k0 = 0; k0 < 4; ++k0)
                b[g][mat][k0] = *reinterpret_cast<const short8*>(
                    &Wt[(size_t)mat * HIDDEN * HIDDEN + n * HIDDEN + k0 * 32 + quad * 8]);
            bias[g][mat] = (mat == 0) ? bq[n] : (mat == 1) ? bk[n] : bv[n];
        }
    }

    #pragma unroll
    for (int mt = 0; mt < 2; ++mt) {
        const int mloc = mt * 16 + l15;          // A row (node within block)
        short8 a[4];
        #pragma unroll
        for (int k0 = 0; k0 < 4; ++k0)           // A[m][k=k0*32+quad*8..+7]
            a[k0] = *reinterpret_cast<const short8*>(
                &hb[mloc * HBS + k0 * 32 + quad * 8]);
        #pragma unroll
        for (int g = 0; g < 2; ++g) {
            const int n = (wave * 2 + g) * 16 + l15;
            f32x4 acc[3] = {{0.f,0.f,0.f,0.f},{0.f,0.f,0.f,0.f},{0.f,0.f,0.f,0.f}};
            #pragma unroll
            for (int mat = 0; mat < 3; ++mat)
                #pragma unroll
                for (int k0 = 0; k0 < 4; ++k0)
                    acc[mat] = __builtin_amdgcn_mfma_f32_16x16x32_bf16(
                        a[k0], b[g][mat][k0], acc[mat], 0, 0, 0);
            #pragma unroll
            for (int mat = 0; mat < 3; ++mat) {
                #pragma unroll
                for (int r = 0; r < 4; ++r) {    // C row = quad*4+r (node in m-tile)
                    int node = n0 + mt * 16 + quad * 4 + r;
                    if (node < N) {
                        float val = acc[mat][r] + bias[g][mat];
                        if (mat == 0)      qf[(size_t)node * HIDDEN + n] = val * 0.25f;
                        else if (mat == 1) kv[(size_t)node * 256 + n] = __float2bfloat16(val);
                        else               kv[(size_t)node * 256 + 128 + n] = __float2bfloat16(val);
                    }
                }
            }
        }
    }
}

// ---------------- Kernel 2: ELL sparse attention (r17: v off the LDS pipe) ----------------
// r16 analysis: dur ~= LDS-pipe time (~56 LDS ops/thread; PV's 2048 ds_read_u16
// per node dominated). r17: v read DIRECTLY global->regs, coalesced (wave covers
// 128B contiguous per j), issued before the score phase to overlap; gather
// stages k-halves only (4-row 1KB groups + 16B pad -> minimal-bank b128 score
// reads AND load_lds16 uniform-base preserved); w via 4x b128 broadcast from
// transposed sl; idx via 4x b128. ~21 LDS ops/thread. Math bit-identical.
#define NPB2 2
#define KGW 520  // shorts per 4-row k group: 4*128 + 8 pad (1040B, 260 words)

__global__ __launch_bounds__(256) void attn_kernel(
    const int* __restrict__ nbr_idx, const int* __restrict__ nbr_mask,
    const float* __restrict__ qf, const __hip_bfloat16* __restrict__ kv,
    float* __restrict__ out, int N)
{
    __shared__ __align__(16) __hip_bfloat16 kl[NPB2][4][KGW];
    __shared__ __align__(16) float sl[NPB2][NHEAD][20];  // [head][16 w + pad]
    __shared__ __align__(16) int idxl[NPB2][KNBR];
    __shared__ int mskl[NPB2][KNBR];

    const int tid = threadIdx.x;
    const int local = tid >> 7; // node within block
    const int t = tid & 127;    // thread within node
    int n = blockIdx.x * NPB2 + local;
    if (n >= N) n = N - 1;  // duplicate work, barrier-safe

    if (t < KNBR) {
        int iv = nbr_idx[(size_t)n * KNBR + t];
        idxl[local][t] = min(max(iv, 0), N - 1);
        mskl[local][t] = nbr_mask[(size_t)n * KNBR + t];
    }
    __syncthreads();

    const int hh = t >> 4;   // head (0..7)
    const int kk = t & 15;   // neighbor (scores) / dim (PV)

    // idx -> regs (4x b128 broadcast)
    int idxr[KNBR];
    {
        const int4* ip = reinterpret_cast<const int4*>(&idxl[local][0]);
        #pragma unroll
        for (int m4 = 0; m4 < 4; ++m4) {
            int4 iv = ip[m4];
            idxr[4 * m4 + 0] = iv.x; idxr[4 * m4 + 1] = iv.y;
            idxr[4 * m4 + 2] = iv.z; idxr[4 * m4 + 3] = iv.w;
        }
    }
    const int mymsk = mskl[local][kk];

    // k gather (k-half only): 4-row 1KB groups; lane l -> row l>>4, 16B chunk l&15
    {
        const int w2 = t >> 6;       // wave within node (uniform)
        const int l = t & 63;
        #pragma unroll
        for (int j2 = 0; j2 < 2; ++j2) {
            int g = j2 * 2 + w2;
            int r = g * 4 + (l >> 4);
            if (mskl[local][r]) {     // masked rows never read (score overwritten)
                const short* src = (const short*)kv
                    + (size_t)idxl[local][r] * 256 + (size_t)(l & 15) * 8;
                load_lds16(src, &kl[local][g][0]);  // + lane*16 implicit
            }
        }
    }

    // v direct global->regs: per j the 128 node-threads read 256B contiguous
    // (wave = 128B) — issued here so latency overlaps the whole score phase
    float vr[KNBR];
    #pragma unroll
    for (int j = 0; j < KNBR; ++j) {
        unsigned int u = *((const unsigned short*)kv + (size_t)idxr[j] * 256 + 128 + t);
        vr[j] = __uint_as_float(u << 16);
    }

    // q -> regs
    float qr[HDIM];
    {
        const float4* qp = reinterpret_cast<const float4*>(
            qf + (size_t)n * HIDDEN + hh * HDIM);
        #pragma unroll
        for (int c4 = 0; c4 < 4; ++c4) {
            float4 qv = qp[c4];
            qr[4 * c4 + 0] = qv.x; qr[4 * c4 + 1] = qv.y;
            qr[4 * c4 + 2] = qv.z; qr[4 * c4 + 3] = qv.w;
        }
    }
    __syncthreads();  // k staged (drains v/q into regs too)

    // scores + butterfly softmax: thread (hh, kk); kk = low 4 lane bits
    {
        const int g = kk >> 2, rg = kk & 3;
        const short8* kb = reinterpret_cast<const short8*>(
            &kl[local][g][rg * 128 + hh * HDIM]);
        short8 k0 = kb[0], k1 = kb[1];
        const __hip_bfloat162* kp0 = reinterpret_cast<const __hip_bfloat162*>(&k0);
        const __hip_bfloat162* kp1 = reinterpret_cast<const __hip_bfloat162*>(&k1);
        float s = 0.f;
        #pragma unroll
        for (int d2 = 0; d2 < 4; ++d2) {
            float2 f0 = __bfloat1622float2(kp0[d2]);
            float2 f1 = __bfloat1622float2(kp1[d2]);
            s += qr[2 * d2] * f0.x + qr[2 * d2 + 1] * f0.y;
            s += qr[8 + 2 * d2] * f1.x + qr[8 + 2 * d2 + 1] * f1.y;
        }
        if (!mymsk) s = -1e9f;       // garbage k for masked rows discarded here
        float m = s;
        m = fmaxf(m, swz_xor<0x041F>(m));
        m = fmaxf(m, swz_xor<0x081F>(m));
        m = fmaxf(m, swz_xor<0x101F>(m));
        m = fmaxf(m, swz_xor<0x201F>(m));
        float e = __expf(s - m);
        float d = e;
        d += swz_xor<0x041F>(d);
        d += swz_xor<0x081F>(d);
        d += swz_xor<0x101F>(d);
        d += swz_xor<0x201F>(d);
        sl[local][hh][kk] = e / d;   // final weight; all-masked -> 1/16 exact
    }
    __syncthreads();

    // PV: w via 4x b128 broadcast; v already in regs -> pure FMA
    {
        float o = 0.f;
        const float4* wp = reinterpret_cast<const float4*>(&sl[local][hh][0]);
        #pragma unroll
        for (int m4 = 0; m4 < 4; ++m4) {
            float4 w4 = wp[m4];
            o += w4.x * vr[4 * m4 + 0] + w4.y * vr[4 * m4 + 1]
               + w4.z * vr[4 * m4 + 2] + w4.w * vr[4 * m4 + 3];
        }
        out[(size_t)n * HIDDEN + t] = o;  // OUTPUT IS FLOAT32 (verified r6)
    }
}

extern "C" void kernel_launch(void* const* d_in, const int* in_sizes, int n_in,
                              void* d_out, int out_size, void* d_ws, size_t ws_size,
                              hipStream_t stream)
{
    float* out = (float*)d_out;

    bool ok = (n_in == 10);
    int N = ok ? in_sizes[0] / NFEAT : 0;
    ok = ok && N > 0 && in_sizes[0] == N * NFEAT
            && in_sizes[1] == N * KNBR
            && in_sizes[2] == N * KNBR
            && in_sizes[3] == NFEAT * VOCAB * HIDDEN
            && in_sizes[4] == HIDDEN * HIDDEN && in_sizes[5] == HIDDEN
            && in_sizes[6] == HIDDEN * HIDDEN && in_sizes[7] == HIDDEN
            && in_sizes[8] == HIDDEN * HIDDEN && in_sizes[9] == HIDDEN
            && out_size == N * HIDDEN;
    if (!ok) {
        fill_kernel<<<(out_size + 255) / 256, 256, 0, stream>>>(out, out_size, 0.0f);
        return;
    }
    size_t need = (size_t)N * 1024 + 3 * HIDDEN * HIDDEN * sizeof(short);
    if (ws_size < need) {
        fill_kernel<<<(out_size + 255) / 256, 256, 0, stream>>>(out, out_size, 1.0f);
        return;
    }

    const int* X        = (const int*)d_in[0];
    const int* nbr_idx  = (const int*)d_in[1];
    const int* nbr_mask = (const int*)d_in[2];
    const float* emb = (const float*)d_in[3];
    const float* Wq  = (const float*)d_in[4];
    const float* bq  = (const float*)d_in[5];
    const float* Wk  = (const float*)d_in[6];
    const float* bk  = (const float*)d_in[7];
    const float* Wv  = (const float*)d_in[8];
    const float* bv  = (const float*)d_in[9];

    // workspace: qf fp32 [N][128] | kv bf16 [N][256] | Wt bf16 [3][128][128]
    float* qf = (float*)d_ws;
    __hip_bfloat16* kv =
        (__hip_bfloat16*)((char*)d_ws + (size_t)N * HIDDEN * sizeof(float));
    short* Wt = (short*)((char*)d_ws + (size_t)N * 1024);

    wt_kernel<<<12, 256, 0, stream>>>(Wq, Wk, Wv, Wt);
    qkv_kernel<<<(N + MT - 1) / MT, 256, 0, stream>>>(
        X, emb, Wt, bq, bk, bv, qf, kv, N);
    attn_kernel<<<(N + NPB2 - 1) / NPB2, 256, 0, stream>>>(
        nbr_idx, nbr_mask, qf, kv, out, N);
}